// Round 2
// baseline (114.032 us; speedup 1.0000x reference)
//
#include <hip/hip_runtime.h>
#include <hip/hip_bf16.h>

// NNConv collapsed algebraically:
//   out = x @ root + bias + mean_broadcast
//   mean[n] = (1/(64*cnt[n])) * sum_{e: col[e]==n} ( ea[e,:] . g[row[e],:] + h[row[e]] )
//   g[n,d]  = sum_c Wsum[d,c] * x[n,c],  Wsum[d,c] = sum_o W_nn[d, c*64+o]
//   h[n]    = sum_c bsum[c]  * x[n,c],  bsum[c]   = sum_o b_nn[c*64+o]

#define CC 64
#define DE 16
#define PAD 65   // xs row stride in k_final: 65%32=1 -> nl groups hit distinct banks

// ---- Kernel 1: zero seg/cnt + Wsum(16x64)/bsum(64), wave-per-output --------
__global__ __launch_bounds__(256) void k_prep(const float* __restrict__ W,
                                              const float* __restrict__ b,
                                              float* __restrict__ wsum,   // 1088 floats
                                              float* __restrict__ zreg,   // seg||cnt
                                              int zcount, int total_waves) {
    int gtid = blockIdx.x * 256 + threadIdx.x;
    for (int i = gtid; i < zcount; i += gridDim.x * 256) zreg[i] = 0.f;

    int lane = threadIdx.x & 63;
    int wid  = gtid >> 6;
    for (int p = wid; p < 1024 + CC; p += total_waves) {
        float v = (p < 1024) ? W[(size_t)p * CC + lane]
                             : b[(size_t)(p - 1024) * CC + lane];
#pragma unroll
        for (int off = 32; off; off >>= 1) v += __shfl_xor(v, off, 64);
        if (lane == 0) wsum[p] = v;
    }
}

// ---- Kernel 2: per-node g (N x 16) and h (N); wsum via uniform s_loads -----
__global__ __launch_bounds__(64) void k_node(const float* __restrict__ x,
                                             const float* __restrict__ wb, // 1024+64
                                             float* __restrict__ g,
                                             float* __restrict__ h,
                                             int N) {
    int n = blockIdx.x * 64 + threadIdx.x;
    if (n >= N) return;

    const float4* x4  = (const float4*)(x + (size_t)n * CC);
    const float4* ws4 = (const float4*)wb;          // ws4[d*16 + c4], uniform idx
    const float4* bs4 = (const float4*)(wb + 1024); // bs4[c4], uniform idx

    float4 xr[16];
#pragma unroll
    for (int i = 0; i < 16; ++i) xr[i] = x4[i];

    float acc[DE];
#pragma unroll
    for (int d = 0; d < DE; ++d) acc[d] = 0.f;
    float hh = 0.f;

#pragma unroll
    for (int c4 = 0; c4 < 16; ++c4) {
        float4 xv = xr[c4];
        float4 bv = bs4[c4];   // uniform -> SGPR
        hh += bv.x * xv.x + bv.y * xv.y + bv.z * xv.z + bv.w * xv.w;
#pragma unroll
        for (int d = 0; d < DE; ++d) {
            float4 wv = ws4[d * 16 + c4];   // uniform -> SGPR
            acc[d] += wv.x * xv.x + wv.y * xv.y + wv.z * xv.z + wv.w * xv.w;
        }
    }
    float4* g4 = (float4*)(g + (size_t)n * DE);
    g4[0] = make_float4(acc[0], acc[1], acc[2], acc[3]);
    g4[1] = make_float4(acc[4], acc[5], acc[6], acc[7]);
    g4[2] = make_float4(acc[8], acc[9], acc[10], acc[11]);
    g4[3] = make_float4(acc[12], acc[13], acc[14], acc[15]);
    h[n] = hh;
}

// ---- Kernel 3: per-edge scalar + scatter -----------------------------------
__global__ __launch_bounds__(256) void k_edge(const int* __restrict__ ei,
                                              const float* __restrict__ ea,
                                              const float* __restrict__ g,
                                              const float* __restrict__ h,
                                              float* __restrict__ seg,
                                              float* __restrict__ cnt,
                                              int E) {
    int e = blockIdx.x * 256 + threadIdx.x;
    if (e >= E) return;
    int r  = ei[e];
    int cn = ei[E + e];
    const float4* a4 = (const float4*)(ea + (size_t)e * DE);
    const float4* g4 = (const float4*)(g + (size_t)r * DE);
    float4 a0 = a4[0], a1 = a4[1], a2 = a4[2], a3 = a4[3];
    float4 g0 = g4[0], g1 = g4[1], g2 = g4[2], g3 = g4[3];
    float s = h[r]
        + a0.x * g0.x + a0.y * g0.y + a0.z * g0.z + a0.w * g0.w
        + a1.x * g1.x + a1.y * g1.y + a1.z * g1.z + a1.w * g1.w
        + a2.x * g2.x + a2.y * g2.y + a2.z * g2.z + a2.w * g2.w
        + a3.x * g3.x + a3.y * g3.y + a3.z * g3.z + a3.w * g3.w;
    atomicAdd(seg + cn, s);
    atomicAdd(cnt + cn, 1.0f);
}

// ---- Kernel 4: out = x @ root + bias + mean; float4 per thread -------------
__global__ __launch_bounds__(256) void k_final(const float* __restrict__ x,
                                               const float* __restrict__ root,
                                               const float* __restrict__ bias,
                                               const float* __restrict__ seg,
                                               const float* __restrict__ cnt,
                                               float* __restrict__ out,
                                               int N) {
    __shared__ float rt[CC * CC];      // 16 KB, same layout as global
    __shared__ float xs[16 * PAD];     // 16 nodes, padded rows
    __shared__ float bi[CC];
    __shared__ float mn[16];
    int tid = threadIdx.x;
    int n0 = blockIdx.x * 16;

#pragma unroll
    for (int i = 0; i < 16; ++i) rt[tid + i * 256] = root[tid + i * 256];
#pragma unroll
    for (int it = 0; it < 4; ++it) {
        int i = it * 256 + tid;                 // 0..1023
        if ((size_t)n0 * CC + i < (size_t)N * CC)
            xs[(i >> 6) * PAD + (i & 63)] = x[(size_t)n0 * CC + i];
    }
    if (tid < CC) bi[tid] = bias[tid];
    if (tid < 16 && n0 + tid < N) {
        float c = cnt[n0 + tid];
        mn[tid] = c > 0.f ? seg[n0 + tid] / (c * (float)CC) : 0.f;
    }
    __syncthreads();

    int nl = tid >> 4, ci = tid & 15;
    int n = n0 + nl;
    if (n >= N) return;

    const float4* rt4 = (const float4*)rt;
    const float4* bi4 = (const float4*)bi;
    float m = mn[nl];
    float4 bv = bi4[ci];
    float4 acc = make_float4(bv.x + m, bv.y + m, bv.z + m, bv.w + m);
#pragma unroll
    for (int k = 0; k < CC; ++k) {
        float a  = xs[nl * PAD + k];        // 4 distinct banks per wave, bcast
        float4 w = rt4[k * 16 + ci];        // 256B row, 2-way alias = free
        acc.x += a * w.x; acc.y += a * w.y; acc.z += a * w.z; acc.w += a * w.w;
    }
    *(float4*)(out + (size_t)n * CC + ci * 4) = acc;
}

extern "C" void kernel_launch(void* const* d_in, const int* in_sizes, int n_in,
                              void* d_out, int out_size, void* d_ws, size_t ws_size,
                              hipStream_t stream) {
    const float* x    = (const float*)d_in[0];
    const int*   ei   = (const int*)  d_in[1];
    const float* ea   = (const float*)d_in[2];
    const float* W    = (const float*)d_in[3];
    const float* b    = (const float*)d_in[4];
    const float* root = (const float*)d_in[5];
    const float* bias = (const float*)d_in[6];
    float* out = (float*)d_out;
    float* ws  = (float*)d_ws;

    const int N = in_sizes[0] / CC;   // 10000
    const int E = in_sizes[1] / 2;    // 100000

    // workspace layout (floats):
    float* wsum = ws;                 // [0, 1088)  Wsum(1024) then bsum(64)
    float* h    = ws + 1088;          // [1088, 1088+N)
    float* seg  = ws + 1088 + N;      // zeroed by k_prep
    float* cnt  = ws + 1088 + 2 * N;  // zeroed by k_prep (contiguous with seg)
    float* g    = ws + 1088 + 3 * N;  // N*16 floats, 16B-aligned

    int zBlocks = (2 * N + 255) / 256;
    int nBlocks = (N + 63) / 64;
    int eBlocks = (E + 255) / 256;
    int fBlocks = (N + 15) / 16;

    k_prep <<<zBlocks, 256, 0, stream>>>(W, b, wsum, seg, 2 * N, zBlocks * 4);
    k_node <<<nBlocks,  64, 0, stream>>>(x, wsum, g, h, N);
    k_edge <<<eBlocks, 256, 0, stream>>>(ei, ea, g, h, seg, cnt, E);
    k_final<<<fBlocks, 256, 0, stream>>>(x, root, bias, seg, cnt, out, N);
}

// Round 3
// 107.031 us; speedup vs baseline: 1.0654x; 1.0654x over previous
//
#include <hip/hip_runtime.h>
#include <hip/hip_bf16.h>

// NNConv collapsed algebraically:
//   out = x @ root + bias + mean_broadcast
//   mean[n] = (1/(64*cnt[n])) * sum_{e: col[e]==n} ( ea[e,:] . g[row[e],:] + h[row[e]] )
//   g[n,d]  = sum_c Wsum[d,c] * x[n,c],  Wsum[d,c] = sum_o W_nn[d, c*64+o]
//   h[n]    = sum_c bsum[c]  * x[n,c],  bsum[c]   = sum_o b_nn[c*64+o]
//
// 3 dispatches: k_node (zero seg/cnt + per-block wsum in LDS + g/h),
//               k_edge (per-edge scalar + atomic scatter),
//               k_final (x@root + bias + mean).

#define CC 64
#define DE 16
#define PAD 65   // xs row stride in k_final: 65%32=1 -> nl groups hit distinct banks

// ---- Kernel 1: zero seg/cnt; per-block Wsum/bsum in LDS; g (Nx16), h (N) ---
__global__ __launch_bounds__(256) void k_node(const float* __restrict__ W,
                                              const float* __restrict__ b,
                                              const float* __restrict__ x,
                                              float* __restrict__ g,
                                              float* __restrict__ h,
                                              float* __restrict__ zreg,  // seg||cnt
                                              int zcount, int N) {
    __shared__ float ws[1024 + CC];
    int tid = threadIdx.x;

    // zero seg/cnt (grid-stride; completes before k_edge by stream order)
    for (int i = blockIdx.x * 256 + tid; i < zcount; i += gridDim.x * 256)
        zreg[i] = 0.f;

    // per-block Wsum/bsum: 1088 reductions of 64 contiguous floats (L2/L3-hot)
    for (int p = tid; p < 1024 + CC; p += 256) {
        const float4* src = (p < 1024) ? (const float4*)(W + (size_t)p * CC)
                                       : (const float4*)(b + (size_t)(p - 1024) * CC);
        float s = 0.f;
#pragma unroll
        for (int i = 0; i < 16; ++i) { float4 v = src[i]; s += v.x + v.y + v.z + v.w; }
        ws[p] = s;
    }
    __syncthreads();

    int n = blockIdx.x * 256 + tid;
    if (n >= N) return;

    const float4* x4  = (const float4*)(x + (size_t)n * CC);
    const float4* ws4 = (const float4*)ws;          // uniform idx -> LDS broadcast
    const float4* bs4 = (const float4*)(ws + 1024);

    float4 xr[16];
#pragma unroll
    for (int i = 0; i < 16; ++i) xr[i] = x4[i];

    float acc[DE];
#pragma unroll
    for (int d = 0; d < DE; ++d) acc[d] = 0.f;
    float hh = 0.f;

#pragma unroll
    for (int c4 = 0; c4 < 16; ++c4) {
        float4 xv = xr[c4];
        float4 bv = bs4[c4];
        hh += bv.x * xv.x + bv.y * xv.y + bv.z * xv.z + bv.w * xv.w;
#pragma unroll
        for (int d = 0; d < DE; ++d) {
            float4 wv = ws4[d * 16 + c4];
            acc[d] += wv.x * xv.x + wv.y * xv.y + wv.z * xv.z + wv.w * xv.w;
        }
    }
    float4* g4 = (float4*)(g + (size_t)n * DE);
    g4[0] = make_float4(acc[0], acc[1], acc[2], acc[3]);
    g4[1] = make_float4(acc[4], acc[5], acc[6], acc[7]);
    g4[2] = make_float4(acc[8], acc[9], acc[10], acc[11]);
    g4[3] = make_float4(acc[12], acc[13], acc[14], acc[15]);
    h[n] = hh;
}

// ---- Kernel 2: per-edge scalar + scatter -----------------------------------
__global__ __launch_bounds__(256) void k_edge(const int* __restrict__ ei,
                                              const float* __restrict__ ea,
                                              const float* __restrict__ g,
                                              const float* __restrict__ h,
                                              float* __restrict__ seg,
                                              float* __restrict__ cnt,
                                              int E) {
    int e = blockIdx.x * 256 + threadIdx.x;
    if (e >= E) return;
    int r  = ei[e];
    int cn = ei[E + e];
    const float4* a4 = (const float4*)(ea + (size_t)e * DE);
    const float4* g4 = (const float4*)(g + (size_t)r * DE);
    float4 a0 = a4[0], a1 = a4[1], a2 = a4[2], a3 = a4[3];
    float4 g0 = g4[0], g1 = g4[1], g2 = g4[2], g3 = g4[3];
    float s = h[r]
        + a0.x * g0.x + a0.y * g0.y + a0.z * g0.z + a0.w * g0.w
        + a1.x * g1.x + a1.y * g1.y + a1.z * g1.z + a1.w * g1.w
        + a2.x * g2.x + a2.y * g2.y + a2.z * g2.z + a2.w * g2.w
        + a3.x * g3.x + a3.y * g3.y + a3.z * g3.z + a3.w * g3.w;
    atomicAdd(seg + cn, s);
    atomicAdd(cnt + cn, 1.0f);
}

// ---- Kernel 3: out = x @ root + bias + mean; float4 per thread -------------
__global__ __launch_bounds__(256) void k_final(const float* __restrict__ x,
                                               const float* __restrict__ root,
                                               const float* __restrict__ bias,
                                               const float* __restrict__ seg,
                                               const float* __restrict__ cnt,
                                               float* __restrict__ out,
                                               int N) {
    __shared__ float rt[CC * CC];      // 16 KB, same layout as global
    __shared__ float xs[16 * PAD];     // 16 nodes, padded rows
    __shared__ float bi[CC];
    __shared__ float mn[16];
    int tid = threadIdx.x;
    int n0 = blockIdx.x * 16;

#pragma unroll
    for (int i = 0; i < 16; ++i) rt[tid + i * 256] = root[tid + i * 256];
#pragma unroll
    for (int it = 0; it < 4; ++it) {
        int i = it * 256 + tid;                 // 0..1023
        if ((size_t)n0 * CC + i < (size_t)N * CC)
            xs[(i >> 6) * PAD + (i & 63)] = x[(size_t)n0 * CC + i];
    }
    if (tid < CC) bi[tid] = bias[tid];
    if (tid < 16 && n0 + tid < N) {
        float c = cnt[n0 + tid];
        mn[tid] = c > 0.f ? seg[n0 + tid] / (c * (float)CC) : 0.f;
    }
    __syncthreads();

    int nl = tid >> 4, ci = tid & 15;
    int n = n0 + nl;
    if (n >= N) return;

    const float4* rt4 = (const float4*)rt;
    const float4* bi4 = (const float4*)bi;
    float m = mn[nl];
    float4 bv = bi4[ci];
    float4 acc = make_float4(bv.x + m, bv.y + m, bv.z + m, bv.w + m);
#pragma unroll
    for (int k = 0; k < CC; ++k) {
        float a  = xs[nl * PAD + k];        // 4 distinct banks per wave, bcast
        float4 w = rt4[k * 16 + ci];        // 256B row, 2-way alias = free
        acc.x += a * w.x; acc.y += a * w.y; acc.z += a * w.z; acc.w += a * w.w;
    }
    *(float4*)(out + (size_t)n * CC + ci * 4) = acc;
}

extern "C" void kernel_launch(void* const* d_in, const int* in_sizes, int n_in,
                              void* d_out, int out_size, void* d_ws, size_t ws_size,
                              hipStream_t stream) {
    const float* x    = (const float*)d_in[0];
    const int*   ei   = (const int*)  d_in[1];
    const float* ea   = (const float*)d_in[2];
    const float* W    = (const float*)d_in[3];
    const float* b    = (const float*)d_in[4];
    const float* root = (const float*)d_in[5];
    const float* bias = (const float*)d_in[6];
    float* out = (float*)d_out;
    float* ws  = (float*)d_ws;

    const int N = in_sizes[0] / CC;   // 10000
    const int E = in_sizes[1] / 2;    // 100000

    // workspace layout (floats):
    float* h    = ws;                 // [0, N)
    float* seg  = ws + N;             // zeroed by k_node
    float* cnt  = ws + 2 * N;         // zeroed by k_node (contiguous with seg)
    float* g    = ws + 3 * N;         // N*16 floats, 16B-aligned (30000*4 % 16 == 0)

    int nBlocks = (N + 255) / 256;    // 40
    int eBlocks = (E + 255) / 256;    // 391
    int fBlocks = (N + 15) / 16;      // 625

    k_node <<<nBlocks, 256, 0, stream>>>(W, b, x, g, h, seg, 2 * N, N);
    k_edge <<<eBlocks, 256, 0, stream>>>(ei, ea, g, h, seg, cnt, E);
    k_final<<<fBlocks, 256, 0, stream>>>(x, root, bias, seg, cnt, out, N);
}